// Round 17
// baseline (274.012 us; speedup 1.0000x reference)
//
#include <hip/hip_runtime.h>

#define N_NODES 50000
#define N_EDGES 800000
#define DIM     128
#define NGRAPH  128
#define NCLASS  10
#define NLAYER  4

#define TEAMS   256
#define ESLICE  (N_EDGES / TEAMS)    // 3125 edges per team slice
#define CWORDS  12500                // 50000 nodes / 4 (nibble-packed bytes per word)
#define DUMMY   50000                // pad node id; hs row 50000 is all-zero

// fused scatter+prep grid layout (1024-thread blocks)
#define SCAT_B  256
#define PRE_B   3126                 // ceil((N+1)*64 / 1024)
#define W_B     8                    // ceil(NLAYER*2048 / 1024)
#define Z_B     17                   // ceil((NGRAPH*DIM + NGRAPH) / 1024)

typedef __attribute__((ext_vector_type(8))) short short8;
typedef __attribute__((ext_vector_type(4))) float floatx4;

__device__ __forceinline__ unsigned f2bf(float f) {
    union { float f; unsigned u; } v; v.f = f;
    return (v.u + 0x7fffu + ((v.u >> 16) & 1u)) >> 16;   // RNE
}
__device__ __forceinline__ float bf_lo(unsigned u) { return __uint_as_float(u << 16); }
__device__ __forceinline__ float bf_hi(unsigned u) { return __uint_as_float(u & 0xffff0000u); }

// ---------------------------------------------------------------------------
// Pass 1: per-team-slice nibble histograms (in=low nibble, out=high nibble,
// one byte per node). Tail: pre-fill colc with DUMMY ids so the gather needs
// no per-edge masking (dummy slots read the all-zero hs row).
__global__ __launch_bounds__(1024) void count_kernel(
    const int* __restrict__ ei, unsigned* __restrict__ cntw,
    unsigned* __restrict__ colc_fill)
{
    __shared__ unsigned h[CWORDS];      // 50 KB
    int team = blockIdx.x, tid = threadIdx.x;
    for (int i = tid; i < CWORDS; i += 1024) h[i] = 0;
    __syncthreads();
    const int e0 = team * ESLICE;
    const int* __restrict__ srcp = ei;
    const int* __restrict__ dstp = ei + N_EDGES;
    for (int e = e0 + tid; e < e0 + ESLICE; e += 1024) {
        int s = srcp[e], d = dstp[e];
        atomicAdd(&h[d >> 2], 1u  << (8 * (d & 3)));   // in-count  (low nibble)
        atomicAdd(&h[s >> 2], 16u << (8 * (s & 3)));   // out-count (high nibble)
    }
    __syncthreads();
    for (int i = tid; i < CWORDS; i += 1024)
        cntw[(size_t)team * CWORDS + i] = h[i];
    // fill colc (as uints) with 0xC350C350 = two ushort DUMMYs
    for (int i = blockIdx.x * 1024 + tid; i < N_NODES * 32; i += TEAMS * 1024)
        colc_fill[i] = 0xC350C350u;
}

// Pass 2: per-node exclusive prefix over the 256 team counts -> exact slot
// offsets. Hierarchical: 4 groups x 32 teams per phase, all 1024 threads
// active; group bases folded into the writeback as a packed-byte add.
__global__ __launch_bounds__(1024) void offsets_kernel(
    const unsigned* __restrict__ cntw, unsigned* __restrict__ offsw,
    unsigned* __restrict__ cnt_dense, float* __restrict__ c_src,
    float* __restrict__ c_dst)
{
    __shared__ unsigned ldsC[128 * 64];   // counts tile  (32 KB)
    __shared__ unsigned ldsO[128 * 64];   // local-prefix tile (32 KB)
    __shared__ unsigned totG[4 * 256];    // per-group (in | out<<16) totals
    __shared__ unsigned baseW[4 * 64];    // packed per-group base bytes
    int tid = threadIdx.x;
    int g = tid >> 8;            // group: 32 teams each within a phase
    int n = tid & 255;           // node-local index
    int n0 = blockIdx.x * 256;
    int w0 = n0 >> 2;
    unsigned carryIn = 0, carryOut = 0;
    for (int ph = 0; ph < 2; ++ph) {
        int t0 = ph * 128;
        for (int i = tid; i < 128 * 64; i += 1024) {
            int tl = i >> 6, wl = i & 63;
            int gw = w0 + wl;
            ldsC[i] = (gw < CWORDS) ? cntw[(size_t)(t0 + tl) * CWORDS + gw] : 0u;
        }
        __syncthreads();
        unsigned locIn = 0, locOut = 0;
        {
            unsigned char* ob = (unsigned char*)ldsO;
            for (int tl = g * 32; tl < g * 32 + 32; ++tl) {
                unsigned wvd = ldsC[tl * 64 + (n >> 2)];
                unsigned b = (wvd >> (8 * (n & 3))) & 255u;
                ob[tl * 256 + n] = (unsigned char)locIn;  // group-local prefix
                locIn  += (b & 15u);
                locOut += (b >> 4);
            }
        }
        totG[g * 256 + n] = locIn | (locOut << 16);
        __syncthreads();
        unsigned baseIn = 0, sumIn = 0, sumOut = 0;
#pragma unroll
        for (int gg = 0; gg < 4; ++gg) {
            unsigned t = totG[gg * 256 + n];
            if (gg < g) baseIn += (t & 0xffffu);
            sumIn += (t & 0xffffu); sumOut += (t >> 16);
        }
        ((unsigned char*)baseW)[g * 256 + n] = (unsigned char)(carryIn + baseIn);
        carryIn += sumIn; carryOut += sumOut;
        __syncthreads();
        for (int i = tid; i < 128 * 64; i += 1024) {
            int tl = i >> 6, wl = i & 63;
            int gw = w0 + wl;
            if (gw < CWORDS)
                offsw[(size_t)(t0 + tl) * CWORDS + gw] =
                    ldsO[i] + baseW[(tl >> 5) * 64 + wl];   // packed byte add
        }
        __syncthreads();
    }
    if (tid < 256) {
        int nn = n0 + tid;
        if (nn < N_NODES) {
            unsigned id_ = carryIn, od = carryOut;
            cnt_dense[nn] = id_ > 64u ? 64u : id_;
            if (id_ < 1u) id_ = 1u;
            if (od < 1u) od = 1u;
            c_dst[nn] = 1.0f / sqrtf((float)id_);
            c_src[nn] = 1.0f / sqrtf((float)od);
        }
    }
}

// Fused pass 3: scatter (blocks 0..255) + prescale (hsA = x*c_src, DUMMY row
// zeroed in both hs buffers) + wprep (W -> MFMA B-fragments) + hg/cntg zero.
__global__ __launch_bounds__(1024) void sp_kernel(
    const int* __restrict__ ei, const unsigned* __restrict__ offsw,
    unsigned short* __restrict__ colc,
    const float2* __restrict__ x, const float* __restrict__ c_src,
    unsigned* __restrict__ hsA, unsigned* __restrict__ hsB,
    const float* __restrict__ W0, const float* __restrict__ Ws,
    uint4* __restrict__ Wf, float* __restrict__ hg, float* __restrict__ cntg)
{
    __shared__ unsigned h[CWORDS];      // 50 KB (scatter blocks only)
    int bid = blockIdx.x, tid = threadIdx.x;
    if (bid < SCAT_B) {
        int team = bid;
        for (int i = tid; i < CWORDS; i += 1024) h[i] = 0;
        __syncthreads();
        const unsigned char* __restrict__ ob =
            (const unsigned char*)offsw + (size_t)team * 50000;
        const int e0 = team * ESLICE;
        const int* __restrict__ srcp = ei;
        const int* __restrict__ dstp = ei + N_EDGES;
        for (int e = e0 + tid; e < e0 + ESLICE; e += 1024) {
            int s = srcp[e], d = dstp[e];
            unsigned old = atomicAdd(&h[d >> 2], 1u << (8 * (d & 3)));
            unsigned pos = (old >> (8 * (d & 3))) & 15u;
            unsigned slot = (unsigned)ob[d] + pos;
            if (slot < 64u) colc[(size_t)d * 64 + slot] = (unsigned short)s;
        }
        return;
    }
    if (bid < SCAT_B + PRE_B) {
        int i = (bid - SCAT_B) * 1024 + tid;     // over (N+1)*64 uints
        if (i >= (N_NODES + 1) * 64) return;
        int row = i >> 6;
        if (row < N_NODES) {
            float c = c_src[row];
            float2 v = x[i];
            hsA[i] = f2bf(v.x * c) | (f2bf(v.y * c) << 16);
        } else {
            hsA[i] = 0u;    // dummy row stays zero through all layers:
            hsB[i] = 0u;    // layer epilogues only write rows < N_NODES
        }
        return;
    }
    if (bid < SCAT_B + PRE_B + W_B) {
        int t = (bid - SCAT_B - PRE_B) * 1024 + tid;
        if (t >= NLAYER * 2048) return;
        int layer = t >> 11;
        int rem = t & 2047;
        int lane = rem & 63;
        int s = (rem >> 6) & 3;
        int c = rem >> 8;
        int quad = lane >> 4, colw = c * 16 + (lane & 15);
        int k0 = s * 32 + quad * 8;
        const float* W = (layer == 0) ? W0 : Ws + (size_t)(layer - 1) * DIM * DIM;
        uint4 p;
        unsigned* pp = (unsigned*)&p;
#pragma unroll
        for (int j = 0; j < 4; ++j) {
            unsigned lo = f2bf(W[(size_t)(k0 + 2 * j) * DIM + colw]);
            unsigned hi = f2bf(W[(size_t)(k0 + 2 * j + 1) * DIM + colw]);
            pp[j] = lo | (hi << 16);
        }
        Wf[t] = p;
        return;
    }
    int idx = (bid - SCAT_B - PRE_B - W_B) * 1024 + tid;
    if (idx < NGRAPH * DIM) hg[idx] = 0.f;
    else if (idx < NGRAPH * DIM + NGRAPH) cntg[idx - NGRAPH * DIM] = 0.f;
}

// Fused conv layer: block = 256 threads = 4 waves owns 16 rows.
// Phase A (4-node interleave + per-node UNIFORM-BRANCH guards): the wave's
//   4 nodes gather in one loop to max(deg), but each node's 8-edge group is
//   guarded by `if (j < deg_i)` -- j and deg_i are wave-uniform, so this is
//   a scalar s_cmp+s_cbranch (no per-lane masking VALU). Cuts padded slots
//   from 4*pad8(max4) (~92) to sum pad8(deg_i) (~80), keeps 32 loads in
//   flight for alive nodes, removes the max-skew tail. readlane broadcasts
//   keep edge ids on the scalar path (no LDS-pipe ops). Remaining pad slots
//   read the DUMMY row (L1-hot zeros). bf16 pack -> XOR-swizzled LDS A-tile.
// Phase B: each wave MFMAs the 16-row tile over 2 of 8 column blocks.
// hs double-buffered across layers (in != out) to avoid cross-block races.
__global__ __launch_bounds__(256) void layer_kernel(
    const unsigned* __restrict__ hs, const unsigned short* __restrict__ colc,
    const unsigned* __restrict__ cnt_dense, const uint4* __restrict__ Wf,
    const float* __restrict__ bias, const float* __restrict__ c_dst,
    const float* __restrict__ c_src, unsigned short* __restrict__ out_bf,
    float* __restrict__ out_f32, int last)
{
    __shared__ unsigned Ash[16 * 64];    // 4 KB A-tile (16 rows x 256 B)
    char* Ab = (char*)Ash;
    int tid = threadIdx.x;
    int lane = tid & 63;
    int wv = __builtin_amdgcn_readfirstlane(tid >> 6);   // uniform wave id
    int r0 = blockIdx.x * 16;            // 3125 * 16 = 50000 exactly
    int nb = r0 + wv * 4;
    const unsigned* __restrict__ cw = (const unsigned*)colc;
    const char* __restrict__ hb = (const char*)hs;
    unsigned loff = (unsigned)(lane << 2);   // byte offset: feats 2*lane..+1

    unsigned dg0 = cnt_dense[nb + 0], dg1 = cnt_dense[nb + 1];
    unsigned dg2 = cnt_dense[nb + 2], dg3 = cnt_dense[nb + 3];
    unsigned m01 = dg0 > dg1 ? dg0 : dg1, m23 = dg2 > dg3 ? dg2 : dg3;
    unsigned mx = m01 > m23 ? m01 : m23;
    unsigned row0 = cw[(unsigned)(nb + 0) * 32u + (unsigned)(lane & 31)];
    unsigned row1 = cw[(unsigned)(nb + 1) * 32u + (unsigned)(lane & 31)];
    unsigned row2 = cw[(unsigned)(nb + 2) * 32u + (unsigned)(lane & 31)];
    unsigned row3 = cw[(unsigned)(nb + 3) * 32u + (unsigned)(lane & 31)];

    float f00 = 0.f, f01 = 0.f, f10 = 0.f, f11 = 0.f;
    float f20 = 0.f, f21 = 0.f, f30 = 0.f, f31 = 0.f;
    for (unsigned j = 0; j < mx; j += 8) {
        int sl = (int)(j >> 1);
        if (j < dg0) {
#pragma unroll
            for (int k = 0; k < 4; ++k) {
                unsigned w = (unsigned)__builtin_amdgcn_readlane((int)row0, sl + k);
                unsigned u0 = *(const unsigned*)(hb + ((w & 0xffffu) << 8) + loff);
                unsigned u1 = *(const unsigned*)(hb + ((w >> 16) << 8) + loff);
                f00 += bf_lo(u0); f01 += bf_hi(u0);
                f00 += bf_lo(u1); f01 += bf_hi(u1);
            }
        }
        if (j < dg1) {
#pragma unroll
            for (int k = 0; k < 4; ++k) {
                unsigned w = (unsigned)__builtin_amdgcn_readlane((int)row1, sl + k);
                unsigned u0 = *(const unsigned*)(hb + ((w & 0xffffu) << 8) + loff);
                unsigned u1 = *(const unsigned*)(hb + ((w >> 16) << 8) + loff);
                f10 += bf_lo(u0); f11 += bf_hi(u0);
                f10 += bf_lo(u1); f11 += bf_hi(u1);
            }
        }
        if (j < dg2) {
#pragma unroll
            for (int k = 0; k < 4; ++k) {
                unsigned w = (unsigned)__builtin_amdgcn_readlane((int)row2, sl + k);
                unsigned u0 = *(const unsigned*)(hb + ((w & 0xffffu) << 8) + loff);
                unsigned u1 = *(const unsigned*)(hb + ((w >> 16) << 8) + loff);
                f20 += bf_lo(u0); f21 += bf_hi(u0);
                f20 += bf_lo(u1); f21 += bf_hi(u1);
            }
        }
        if (j < dg3) {
#pragma unroll
            for (int k = 0; k < 4; ++k) {
                unsigned w = (unsigned)__builtin_amdgcn_readlane((int)row3, sl + k);
                unsigned u0 = *(const unsigned*)(hb + ((w & 0xffffu) << 8) + loff);
                unsigned u1 = *(const unsigned*)(hb + ((w >> 16) << 8) + loff);
                f30 += bf_lo(u0); f31 += bf_hi(u0);
                f30 += bf_lo(u1); f31 += bf_hi(u1);
            }
        }
    }
    {
        int il = wv * 4;
        *(unsigned*)(Ab + il * 256 + ((lane << 2) ^ ((il & 7) << 4))) =
            f2bf(f00) | (f2bf(f01) << 16);
        il++;
        *(unsigned*)(Ab + il * 256 + ((lane << 2) ^ ((il & 7) << 4))) =
            f2bf(f10) | (f2bf(f11) << 16);
        il++;
        *(unsigned*)(Ab + il * 256 + ((lane << 2) ^ ((il & 7) << 4))) =
            f2bf(f20) | (f2bf(f21) << 16);
        il++;
        *(unsigned*)(Ab + il * 256 + ((lane << 2) ^ ((il & 7) << 4))) =
            f2bf(f30) | (f2bf(f31) << 16);
    }
    __syncthreads();

    int quad = lane >> 4, m16 = lane & 15;
    union U { uint4 u; short8 s; };
    U a[4];
#pragma unroll
    for (int s = 0; s < 4; ++s)
        a[s].u = *(const uint4*)(
            Ab + m16 * 256 + ((s * 64 + quad * 16) ^ ((m16 & 7) << 4)));

    floatx4 acc[2];
#pragma unroll
    for (int cc = 0; cc < 2; ++cc) {
        int c = wv * 2 + cc;
        floatx4 ac = {0.f, 0.f, 0.f, 0.f};
#pragma unroll
        for (int s = 0; s < 4; ++s) {
            U b; b.u = Wf[(c * 4 + s) * 64 + lane];
            ac = __builtin_amdgcn_mfma_f32_16x16x32_bf16(a[s].s, b.s, ac, 0, 0, 0);
        }
        acc[cc] = ac;
    }

    float cd[4], cs[4];
#pragma unroll
    for (int r = 0; r < 4; ++r) {
        int row = r0 + quad * 4 + r;
        cd[r] = c_dst[row];
        cs[r] = last ? 1.f : c_src[row];
    }
#pragma unroll
    for (int cc = 0; cc < 2; ++cc) {
        int colg = (wv * 2 + cc) * 16 + m16;
        float b = bias[colg];
#pragma unroll
        for (int r = 0; r < 4; ++r) {
            int row = r0 + quad * 4 + r;
            float v = acc[cc][r] * cd[r] + b;
            v = v > 0.f ? v : 0.f;
            if (last) out_f32[(size_t)row * DIM + colg] = v;
            else      out_bf[(size_t)row * DIM + colg] = (unsigned short)f2bf(v * cs[r]);
        }
    }
}

// Mean-pool readout on sorted graph_ids (fp32 h).
__global__ __launch_bounds__(128) void readout_kernel(
    const float* __restrict__ h, const int* __restrict__ gid,
    float* __restrict__ hg, float* __restrict__ cntg)
{
    int j  = threadIdx.x;
    int n0 = blockIdx.x * 64;
    float acc = 0.f; int cur = -1; int run = 0;
    for (int i = 0; i < 64; ++i) {
        int n = n0 + i;
        if (n >= N_NODES) break;
        int g = gid[n];
        if (g != cur) {
            if (cur >= 0) {
                atomicAdd(&hg[cur * DIM + j], acc);
                if (j == 0) atomicAdd(&cntg[cur], (float)run);
            }
            cur = g; acc = 0.f; run = 0;
        }
        acc += h[(size_t)n * DIM + j];
        run++;
    }
    if (cur >= 0) {
        atomicAdd(&hg[cur * DIM + j], acc);
        if (j == 0) atomicAdd(&cntg[cur], (float)run);
    }
}

__global__ __launch_bounds__(256) void head_kernel(
    const float* __restrict__ hg, const float* __restrict__ cntg,
    const float* __restrict__ Wc, const float* __restrict__ bc,
    float* __restrict__ out)
{
    int idx = blockIdx.x * blockDim.x + threadIdx.x;
    if (idx >= NGRAPH * NCLASS) return;
    int g = idx / NCLASS, c = idx % NCLASS;
    float inv = 1.0f / fmaxf(cntg[g], 1.0f);
    float s = 0.f;
    for (int j = 0; j < DIM; ++j) s = fmaf(hg[g * DIM + j], Wc[j * NCLASS + c], s);
    out[idx] = s * inv + bc[c];
}

// ---------------------------------------------------------------------------
extern "C" void kernel_launch(void* const* d_in, const int* in_sizes, int n_in,
                              void* d_out, int out_size, void* d_ws, size_t ws_size,
                              hipStream_t stream)
{
    const float* x   = (const float*)d_in[0];
    const float* W0  = (const float*)d_in[1];
    const float* b0  = (const float*)d_in[2];
    const float* Ws  = (const float*)d_in[3];
    const float* bs  = (const float*)d_in[4];
    const float* Wc  = (const float*)d_in[5];
    const float* bc  = (const float*)d_in[6];
    const int*   ei  = (const int*)d_in[7];
    const int*   gid = (const int*)d_in[8];
    float* out = (float*)d_out;

    char* ws = (char*)d_ws;
    size_t o = 0;
    auto alloc = [&](size_t bytes) {
        size_t r = o; o = (o + bytes + 255) & ~(size_t)255; return r;
    };
    unsigned* cntw      = (unsigned*)(ws + alloc((size_t)TEAMS * CWORDS * 4));
    unsigned* offsw     = (unsigned*)(ws + alloc((size_t)TEAMS * CWORDS * 4));
    unsigned* cnt_dense = (unsigned*)(ws + alloc((size_t)N_NODES * 4));
    float*    c_src     = (float*)(ws + alloc((size_t)N_NODES * 4));
    float*    c_dst     = (float*)(ws + alloc((size_t)N_NODES * 4));
    unsigned short* colc = (unsigned short*)(ws + alloc((size_t)N_NODES * 64 * 2));
    unsigned* hsA       = (unsigned*)(ws + alloc((size_t)(N_NODES + 1) * 64 * 4));
    unsigned* hsB       = (unsigned*)(ws + alloc((size_t)(N_NODES + 1) * 64 * 4));
    float*    hlast     = (float*)(ws + alloc((size_t)N_NODES * DIM * 4));
    uint4*    Wf        = (uint4*)(ws + alloc((size_t)NLAYER * 2048 * 16));
    float*    hg        = (float*)(ws + alloc((size_t)NGRAPH * DIM * 4));
    float*    cntg      = (float*)(ws + alloc((size_t)NGRAPH * 4));

    count_kernel<<<TEAMS, 1024, 0, stream>>>(ei, cntw, (unsigned*)colc);
    offsets_kernel<<<(N_NODES + 255) / 256, 1024, 0, stream>>>(
        cntw, offsw, cnt_dense, c_src, c_dst);
    sp_kernel<<<SCAT_B + PRE_B + W_B + Z_B, 1024, 0, stream>>>(
        ei, offsw, colc, (const float2*)x, c_src, hsA, hsB, W0, Ws, Wf, hg, cntg);

    const int LAYER_BLOCKS = N_NODES / 16;   // 3125, exact

    for (int l = 0; l < NLAYER; ++l) {
        const float* b = (l == 0) ? b0 : (bs + (size_t)(l - 1) * DIM);
        int last = (l == NLAYER - 1) ? 1 : 0;
        const unsigned* hin = (l & 1) ? hsB : hsA;
        unsigned* hout      = (l & 1) ? hsA : hsB;
        layer_kernel<<<LAYER_BLOCKS, 256, 0, stream>>>(
            hin, colc, cnt_dense, Wf + (size_t)l * 2048, b, c_dst, c_src,
            (unsigned short*)hout, hlast, last);
    }

    readout_kernel<<<(N_NODES + 63) / 64, 128, 0, stream>>>(hlast, gid, hg, cntg);
    head_kernel<<<(NGRAPH * NCLASS + 255) / 256, 256, 0, stream>>>(hg, cntg, Wc, bc, out);
}

// Round 18
// 272.485 us; speedup vs baseline: 1.0056x; 1.0056x over previous
//
#include <hip/hip_runtime.h>

#define N_NODES 50000
#define N_EDGES 800000
#define DIM     128
#define NGRAPH  128
#define NCLASS  10
#define NLAYER  4

#define TEAMS   256
#define ESLICE  (N_EDGES / TEAMS)    // 3125 edges per team slice
#define CWORDS  12500                // 50000 nodes / 4 (nibble-packed bytes per word)
#define DUMMY   50000                // pad node id; hs row 50000 is all-zero

// fused scatter+prep grid layout (1024-thread blocks)
#define SCAT_B  256
#define PRE_B   3126                 // ceil((N+1)*64 / 1024)
#define W_B     8                    // ceil(NLAYER*2048 / 1024)

typedef __attribute__((ext_vector_type(8))) short short8;
typedef __attribute__((ext_vector_type(4))) float floatx4;

__device__ __forceinline__ unsigned f2bf(float f) {
    union { float f; unsigned u; } v; v.f = f;
    return (v.u + 0x7fffu + ((v.u >> 16) & 1u)) >> 16;   // RNE
}
__device__ __forceinline__ float bf_lo(unsigned u) { return __uint_as_float(u << 16); }
__device__ __forceinline__ float bf_hi(unsigned u) { return __uint_as_float(u & 0xffff0000u); }

// ---------------------------------------------------------------------------
// Pass 1: per-team-slice nibble histograms (in=low nibble, out=high nibble,
// one byte per node). Tail: pre-fill colc with DUMMY ids so the gather needs
// no per-edge masking (dummy slots read the all-zero hs row).
__global__ __launch_bounds__(1024) void count_kernel(
    const int* __restrict__ ei, unsigned* __restrict__ cntw,
    unsigned* __restrict__ colc_fill)
{
    __shared__ unsigned h[CWORDS];      // 50 KB
    int team = blockIdx.x, tid = threadIdx.x;
    for (int i = tid; i < CWORDS; i += 1024) h[i] = 0;
    __syncthreads();
    const int e0 = team * ESLICE;
    const int* __restrict__ srcp = ei;
    const int* __restrict__ dstp = ei + N_EDGES;
    for (int e = e0 + tid; e < e0 + ESLICE; e += 1024) {
        int s = srcp[e], d = dstp[e];
        atomicAdd(&h[d >> 2], 1u  << (8 * (d & 3)));   // in-count  (low nibble)
        atomicAdd(&h[s >> 2], 16u << (8 * (s & 3)));   // out-count (high nibble)
    }
    __syncthreads();
    for (int i = tid; i < CWORDS; i += 1024)
        cntw[(size_t)team * CWORDS + i] = h[i];
    // fill colc (as uints) with 0xC350C350 = two ushort DUMMYs
    for (int i = blockIdx.x * 1024 + tid; i < N_NODES * 32; i += TEAMS * 1024)
        colc_fill[i] = 0xC350C350u;
}

// Pass 2: per-node exclusive prefix over the 256 team counts -> exact slot
// offsets. Hierarchical: 4 groups x 32 teams per phase, all 1024 threads
// active; group bases folded into the writeback as a packed-byte add.
__global__ __launch_bounds__(1024) void offsets_kernel(
    const unsigned* __restrict__ cntw, unsigned* __restrict__ offsw,
    unsigned* __restrict__ cnt_dense, float* __restrict__ c_src,
    float* __restrict__ c_dst)
{
    __shared__ unsigned ldsC[128 * 64];   // counts tile  (32 KB)
    __shared__ unsigned ldsO[128 * 64];   // local-prefix tile (32 KB)
    __shared__ unsigned totG[4 * 256];    // per-group (in | out<<16) totals
    __shared__ unsigned baseW[4 * 64];    // packed per-group base bytes
    int tid = threadIdx.x;
    int g = tid >> 8;            // group: 32 teams each within a phase
    int n = tid & 255;           // node-local index
    int n0 = blockIdx.x * 256;
    int w0 = n0 >> 2;
    unsigned carryIn = 0, carryOut = 0;
    for (int ph = 0; ph < 2; ++ph) {
        int t0 = ph * 128;
        for (int i = tid; i < 128 * 64; i += 1024) {
            int tl = i >> 6, wl = i & 63;
            int gw = w0 + wl;
            ldsC[i] = (gw < CWORDS) ? cntw[(size_t)(t0 + tl) * CWORDS + gw] : 0u;
        }
        __syncthreads();
        unsigned locIn = 0, locOut = 0;
        {
            unsigned char* ob = (unsigned char*)ldsO;
            for (int tl = g * 32; tl < g * 32 + 32; ++tl) {
                unsigned wvd = ldsC[tl * 64 + (n >> 2)];
                unsigned b = (wvd >> (8 * (n & 3))) & 255u;
                ob[tl * 256 + n] = (unsigned char)locIn;  // group-local prefix
                locIn  += (b & 15u);
                locOut += (b >> 4);
            }
        }
        totG[g * 256 + n] = locIn | (locOut << 16);
        __syncthreads();
        unsigned baseIn = 0, sumIn = 0, sumOut = 0;
#pragma unroll
        for (int gg = 0; gg < 4; ++gg) {
            unsigned t = totG[gg * 256 + n];
            if (gg < g) baseIn += (t & 0xffffu);
            sumIn += (t & 0xffffu); sumOut += (t >> 16);
        }
        ((unsigned char*)baseW)[g * 256 + n] = (unsigned char)(carryIn + baseIn);
        carryIn += sumIn; carryOut += sumOut;
        __syncthreads();
        for (int i = tid; i < 128 * 64; i += 1024) {
            int tl = i >> 6, wl = i & 63;
            int gw = w0 + wl;
            if (gw < CWORDS)
                offsw[(size_t)(t0 + tl) * CWORDS + gw] =
                    ldsO[i] + baseW[(tl >> 5) * 64 + wl];   // packed byte add
        }
        __syncthreads();
    }
    if (tid < 256) {
        int nn = n0 + tid;
        if (nn < N_NODES) {
            unsigned id_ = carryIn, od = carryOut;
            cnt_dense[nn] = id_ > 64u ? 64u : id_;
            if (id_ < 1u) id_ = 1u;
            if (od < 1u) od = 1u;
            c_dst[nn] = 1.0f / sqrtf((float)id_);
            c_src[nn] = 1.0f / sqrtf((float)od);
        }
    }
}

// Fused pass 3: scatter (blocks 0..255) + prescale (hsA = x*c_src, DUMMY row
// zeroed in both hs buffers) + wprep (W -> MFMA B-fragments).
__global__ __launch_bounds__(1024) void sp_kernel(
    const int* __restrict__ ei, const unsigned* __restrict__ offsw,
    unsigned short* __restrict__ colc,
    const float2* __restrict__ x, const float* __restrict__ c_src,
    unsigned* __restrict__ hsA, unsigned* __restrict__ hsB,
    const float* __restrict__ W0, const float* __restrict__ Ws,
    uint4* __restrict__ Wf)
{
    __shared__ unsigned h[CWORDS];      // 50 KB (scatter blocks only)
    int bid = blockIdx.x, tid = threadIdx.x;
    if (bid < SCAT_B) {
        int team = bid;
        for (int i = tid; i < CWORDS; i += 1024) h[i] = 0;
        __syncthreads();
        const unsigned char* __restrict__ ob =
            (const unsigned char*)offsw + (size_t)team * 50000;
        const int e0 = team * ESLICE;
        const int* __restrict__ srcp = ei;
        const int* __restrict__ dstp = ei + N_EDGES;
        for (int e = e0 + tid; e < e0 + ESLICE; e += 1024) {
            int s = srcp[e], d = dstp[e];
            unsigned old = atomicAdd(&h[d >> 2], 1u << (8 * (d & 3)));
            unsigned pos = (old >> (8 * (d & 3))) & 15u;
            unsigned slot = (unsigned)ob[d] + pos;
            if (slot < 64u) colc[(size_t)d * 64 + slot] = (unsigned short)s;
        }
        return;
    }
    if (bid < SCAT_B + PRE_B) {
        int i = (bid - SCAT_B) * 1024 + tid;     // over (N+1)*64 uints
        if (i >= (N_NODES + 1) * 64) return;
        int row = i >> 6;
        if (row < N_NODES) {
            float c = c_src[row];
            float2 v = x[i];
            hsA[i] = f2bf(v.x * c) | (f2bf(v.y * c) << 16);
        } else {
            hsA[i] = 0u;    // dummy row stays zero through all layers:
            hsB[i] = 0u;    // layer epilogues only write rows < N_NODES
        }
        return;
    }
    int t = (bid - SCAT_B - PRE_B) * 1024 + tid;
    if (t >= NLAYER * 2048) return;
    int layer = t >> 11;
    int rem = t & 2047;
    int lane = rem & 63;
    int s = (rem >> 6) & 3;
    int c = rem >> 8;
    int quad = lane >> 4, colw = c * 16 + (lane & 15);
    int k0 = s * 32 + quad * 8;
    const float* W = (layer == 0) ? W0 : Ws + (size_t)(layer - 1) * DIM * DIM;
    uint4 p;
    unsigned* pp = (unsigned*)&p;
#pragma unroll
    for (int j = 0; j < 4; ++j) {
        unsigned lo = f2bf(W[(size_t)(k0 + 2 * j) * DIM + colw]);
        unsigned hi = f2bf(W[(size_t)(k0 + 2 * j + 1) * DIM + colw]);
        pp[j] = lo | (hi << 16);
    }
    Wf[t] = p;
}

// Fused conv layer: block = 256 threads = 4 waves owns 16 rows.
// Phase A (4-node interleaved scalar-broadcast gather): the wave's 4 nodes
//   gather in ONE max(deg) loop -> 32 loads in flight; readlane broadcasts
//   keep the edge id on the scalar path (no LDS-pipe cross-lane ops).
//   Short nodes' tail slots read the DUMMY row (L1-hot zeros) -
//   masking-free. bf16 pack -> XOR-swizzled LDS A-tile.
//   (R17 A/B: per-node uniform-branch guards REGRESSED +7.5us - branch
//   regions fragment the 32-load issue burst; keep the flat interleave.)
// Phase B: each wave MFMAs the 16-row tile over 2 of 8 column blocks.
// hs double-buffered across layers (in != out) to avoid cross-block races.
__global__ __launch_bounds__(256) void layer_kernel(
    const unsigned* __restrict__ hs, const unsigned short* __restrict__ colc,
    const unsigned* __restrict__ cnt_dense, const uint4* __restrict__ Wf,
    const float* __restrict__ bias, const float* __restrict__ c_dst,
    const float* __restrict__ c_src, unsigned short* __restrict__ out_bf,
    float* __restrict__ out_f32, int last)
{
    __shared__ unsigned Ash[16 * 64];    // 4 KB A-tile (16 rows x 256 B)
    char* Ab = (char*)Ash;
    int tid = threadIdx.x;
    int lane = tid & 63;
    int wv = __builtin_amdgcn_readfirstlane(tid >> 6);   // uniform wave id
    int r0 = blockIdx.x * 16;            // 3125 * 16 = 50000 exactly
    int nb = r0 + wv * 4;
    const unsigned* __restrict__ cw = (const unsigned*)colc;
    const char* __restrict__ hb = (const char*)hs;
    unsigned loff = (unsigned)(lane << 2);   // byte offset: feats 2*lane..+1

    unsigned dg0 = cnt_dense[nb + 0], dg1 = cnt_dense[nb + 1];
    unsigned dg2 = cnt_dense[nb + 2], dg3 = cnt_dense[nb + 3];
    unsigned m01 = dg0 > dg1 ? dg0 : dg1, m23 = dg2 > dg3 ? dg2 : dg3;
    unsigned mx = m01 > m23 ? m01 : m23;
    unsigned row0 = cw[(unsigned)(nb + 0) * 32u + (unsigned)(lane & 31)];
    unsigned row1 = cw[(unsigned)(nb + 1) * 32u + (unsigned)(lane & 31)];
    unsigned row2 = cw[(unsigned)(nb + 2) * 32u + (unsigned)(lane & 31)];
    unsigned row3 = cw[(unsigned)(nb + 3) * 32u + (unsigned)(lane & 31)];

    float f00 = 0.f, f01 = 0.f, f10 = 0.f, f11 = 0.f;
    float f20 = 0.f, f21 = 0.f, f30 = 0.f, f31 = 0.f;
    for (unsigned j = 0; j < mx; j += 8) {
#pragma unroll
        for (int k = 0; k < 4; ++k) {     // per k: 1 word per node = 8 edges
            int sl = (int)(j >> 1) + k;
            unsigned w0 = (unsigned)__builtin_amdgcn_readlane((int)row0, sl);
            unsigned w1 = (unsigned)__builtin_amdgcn_readlane((int)row1, sl);
            unsigned w2 = (unsigned)__builtin_amdgcn_readlane((int)row2, sl);
            unsigned w3 = (unsigned)__builtin_amdgcn_readlane((int)row3, sl);
            unsigned u00 = *(const unsigned*)(hb + ((w0 & 0xffffu) << 8) + loff);
            unsigned u01 = *(const unsigned*)(hb + ((w0 >> 16) << 8) + loff);
            unsigned u10 = *(const unsigned*)(hb + ((w1 & 0xffffu) << 8) + loff);
            unsigned u11 = *(const unsigned*)(hb + ((w1 >> 16) << 8) + loff);
            unsigned u20 = *(const unsigned*)(hb + ((w2 & 0xffffu) << 8) + loff);
            unsigned u21 = *(const unsigned*)(hb + ((w2 >> 16) << 8) + loff);
            unsigned u30 = *(const unsigned*)(hb + ((w3 & 0xffffu) << 8) + loff);
            unsigned u31 = *(const unsigned*)(hb + ((w3 >> 16) << 8) + loff);
            f00 += bf_lo(u00); f01 += bf_hi(u00);
            f00 += bf_lo(u01); f01 += bf_hi(u01);
            f10 += bf_lo(u10); f11 += bf_hi(u10);
            f10 += bf_lo(u11); f11 += bf_hi(u11);
            f20 += bf_lo(u20); f21 += bf_hi(u20);
            f20 += bf_lo(u21); f21 += bf_hi(u21);
            f30 += bf_lo(u30); f31 += bf_hi(u30);
            f30 += bf_lo(u31); f31 += bf_hi(u31);
        }
    }
    {
        int il = wv * 4;
        *(unsigned*)(Ab + il * 256 + ((lane << 2) ^ ((il & 7) << 4))) =
            f2bf(f00) | (f2bf(f01) << 16);
        il++;
        *(unsigned*)(Ab + il * 256 + ((lane << 2) ^ ((il & 7) << 4))) =
            f2bf(f10) | (f2bf(f11) << 16);
        il++;
        *(unsigned*)(Ab + il * 256 + ((lane << 2) ^ ((il & 7) << 4))) =
            f2bf(f20) | (f2bf(f21) << 16);
        il++;
        *(unsigned*)(Ab + il * 256 + ((lane << 2) ^ ((il & 7) << 4))) =
            f2bf(f30) | (f2bf(f31) << 16);
    }
    __syncthreads();

    int quad = lane >> 4, m16 = lane & 15;
    union U { uint4 u; short8 s; };
    U a[4];
#pragma unroll
    for (int s = 0; s < 4; ++s)
        a[s].u = *(const uint4*)(
            Ab + m16 * 256 + ((s * 64 + quad * 16) ^ ((m16 & 7) << 4)));

    floatx4 acc[2];
#pragma unroll
    for (int cc = 0; cc < 2; ++cc) {
        int c = wv * 2 + cc;
        floatx4 ac = {0.f, 0.f, 0.f, 0.f};
#pragma unroll
        for (int s = 0; s < 4; ++s) {
            U b; b.u = Wf[(c * 4 + s) * 64 + lane];
            ac = __builtin_amdgcn_mfma_f32_16x16x32_bf16(a[s].s, b.s, ac, 0, 0, 0);
        }
        acc[cc] = ac;
    }

    float cd[4], cs[4];
#pragma unroll
    for (int r = 0; r < 4; ++r) {
        int row = r0 + quad * 4 + r;
        cd[r] = c_dst[row];
        cs[r] = last ? 1.f : c_src[row];
    }
#pragma unroll
    for (int cc = 0; cc < 2; ++cc) {
        int colg = (wv * 2 + cc) * 16 + m16;
        float b = bias[colg];
#pragma unroll
        for (int r = 0; r < 4; ++r) {
            int row = r0 + quad * 4 + r;
            float v = acc[cc][r] * cd[r] + b;
            v = v > 0.f ? v : 0.f;
            if (last) out_f32[(size_t)row * DIM + colg] = v;
            else      out_bf[(size_t)row * DIM + colg] = (unsigned short)f2bf(v * cs[r]);
        }
    }
}

// Fused readout+head: one block per graph. gid is sorted, so graph
// boundaries come from two binary searches (uniform, scalar). 512 threads:
// thread t accumulates col (t&127) over nodes start+(t>>7) stride 4 --
// parallel streaming (vs the old serial 64-iter scan), zero atomics, no
// hg/cntg buffers or zeroing, one launch instead of two.
__global__ __launch_bounds__(512) void graph_kernel(
    const float* __restrict__ h, const int* __restrict__ gid,
    const float* __restrict__ Wc, const float* __restrict__ bc,
    float* __restrict__ out)
{
    __shared__ float part[512];
    __shared__ float hgv[DIM];
    int g = blockIdx.x;               // 0..NGRAPH-1
    int tid = threadIdx.x;
    // lower_bound(g) and lower_bound(g+1) on sorted gid
    int lo = 0, hi = N_NODES;
    while (lo < hi) { int mid = (lo + hi) >> 1; if (gid[mid] < g) lo = mid + 1; else hi = mid; }
    int start = lo;
    hi = N_NODES;
    while (lo < hi) { int mid = (lo + hi) >> 1; if (gid[mid] < g + 1) lo = mid + 1; else hi = mid; }
    int end = lo;

    int j = tid & 127, q = tid >> 7;  // q in 0..3
    float acc = 0.f;
    for (int n = start + q; n < end; n += 4)
        acc += h[(size_t)n * DIM + j];
    part[tid] = acc;
    __syncthreads();
    if (tid < DIM) {
        float s = part[tid] + part[tid + 128] + part[tid + 256] + part[tid + 384];
        hgv[tid] = s / fmaxf((float)(end - start), 1.0f);
    }
    __syncthreads();
    if (tid < NCLASS) {
        float s = 0.f;
#pragma unroll 8
        for (int jj = 0; jj < DIM; ++jj)
            s = fmaf(hgv[jj], Wc[jj * NCLASS + tid], s);
        out[g * NCLASS + tid] = s + bc[tid];
    }
}

// ---------------------------------------------------------------------------
extern "C" void kernel_launch(void* const* d_in, const int* in_sizes, int n_in,
                              void* d_out, int out_size, void* d_ws, size_t ws_size,
                              hipStream_t stream)
{
    const float* x   = (const float*)d_in[0];
    const float* W0  = (const float*)d_in[1];
    const float* b0  = (const float*)d_in[2];
    const float* Ws  = (const float*)d_in[3];
    const float* bs  = (const float*)d_in[4];
    const float* Wc  = (const float*)d_in[5];
    const float* bc  = (const float*)d_in[6];
    const int*   ei  = (const int*)d_in[7];
    const int*   gid = (const int*)d_in[8];
    float* out = (float*)d_out;

    char* ws = (char*)d_ws;
    size_t o = 0;
    auto alloc = [&](size_t bytes) {
        size_t r = o; o = (o + bytes + 255) & ~(size_t)255; return r;
    };
    unsigned* cntw      = (unsigned*)(ws + alloc((size_t)TEAMS * CWORDS * 4));
    unsigned* offsw     = (unsigned*)(ws + alloc((size_t)TEAMS * CWORDS * 4));
    unsigned* cnt_dense = (unsigned*)(ws + alloc((size_t)N_NODES * 4));
    float*    c_src     = (float*)(ws + alloc((size_t)N_NODES * 4));
    float*    c_dst     = (float*)(ws + alloc((size_t)N_NODES * 4));
    unsigned short* colc = (unsigned short*)(ws + alloc((size_t)N_NODES * 64 * 2));
    unsigned* hsA       = (unsigned*)(ws + alloc((size_t)(N_NODES + 1) * 64 * 4));
    unsigned* hsB       = (unsigned*)(ws + alloc((size_t)(N_NODES + 1) * 64 * 4));
    float*    hlast     = (float*)(ws + alloc((size_t)N_NODES * DIM * 4));
    uint4*    Wf        = (uint4*)(ws + alloc((size_t)NLAYER * 2048 * 16));

    count_kernel<<<TEAMS, 1024, 0, stream>>>(ei, cntw, (unsigned*)colc);
    offsets_kernel<<<(N_NODES + 255) / 256, 1024, 0, stream>>>(
        cntw, offsw, cnt_dense, c_src, c_dst);
    sp_kernel<<<SCAT_B + PRE_B + W_B, 1024, 0, stream>>>(
        ei, offsw, colc, (const float2*)x, c_src, hsA, hsB, W0, Ws, Wf);

    const int LAYER_BLOCKS = N_NODES / 16;   // 3125, exact

    for (int l = 0; l < NLAYER; ++l) {
        const float* b = (l == 0) ? b0 : (bs + (size_t)(l - 1) * DIM);
        int last = (l == NLAYER - 1) ? 1 : 0;
        const unsigned* hin = (l & 1) ? hsB : hsA;
        unsigned* hout      = (l & 1) ? hsA : hsB;
        layer_kernel<<<LAYER_BLOCKS, 256, 0, stream>>>(
            hin, colc, cnt_dense, Wf + (size_t)l * 2048, b, c_dst, c_src,
            (unsigned short*)hout, hlast, last);
    }

    graph_kernel<<<NGRAPH, 512, 0, stream>>>(hlast, gid, Wc, bc, out);
}

// Round 19
// 256.295 us; speedup vs baseline: 1.0691x; 1.0632x over previous
//
#include <hip/hip_runtime.h>

#define N_NODES 50000
#define N_EDGES 800000
#define DIM     128
#define NGRAPH  128
#define NCLASS  10
#define NLAYER  4

#define TEAMS   256
#define ESLICE  (N_EDGES / TEAMS)    // 3125 edges per team slice
#define CWORDS  12500                // 50000 nodes / 4 (nibble-packed bytes per word)
#define DUMMY   50000                // pad node id; hs row 50000 is all-zero

// fused scatter+prep grid layout (1024-thread blocks)
#define SCAT_B  256
#define PRE_B   3126                 // ceil((N+1)*64 / 1024)
#define W_B     8                    // ceil(NLAYER*2048 / 1024)

typedef __attribute__((ext_vector_type(8))) short short8;
typedef __attribute__((ext_vector_type(4))) float floatx4;

__device__ __forceinline__ unsigned f2bf(float f) {
    union { float f; unsigned u; } v; v.f = f;
    return (v.u + 0x7fffu + ((v.u >> 16) & 1u)) >> 16;   // RNE
}
__device__ __forceinline__ float bf_lo(unsigned u) { return __uint_as_float(u << 16); }
__device__ __forceinline__ float bf_hi(unsigned u) { return __uint_as_float(u & 0xffff0000u); }

// ---------------------------------------------------------------------------
// Pass 1: per-team-slice nibble histograms (in=low nibble, out=high nibble,
// one byte per node). Tail: pre-fill colc with DUMMY ids so the gather needs
// no per-edge masking (dummy slots read the all-zero hs row).
__global__ __launch_bounds__(1024) void count_kernel(
    const int* __restrict__ ei, unsigned* __restrict__ cntw,
    unsigned* __restrict__ colc_fill)
{
    __shared__ unsigned h[CWORDS];      // 50 KB
    int team = blockIdx.x, tid = threadIdx.x;
    for (int i = tid; i < CWORDS; i += 1024) h[i] = 0;
    __syncthreads();
    const int e0 = team * ESLICE;
    const int* __restrict__ srcp = ei;
    const int* __restrict__ dstp = ei + N_EDGES;
    for (int e = e0 + tid; e < e0 + ESLICE; e += 1024) {
        int s = srcp[e], d = dstp[e];
        atomicAdd(&h[d >> 2], 1u  << (8 * (d & 3)));   // in-count  (low nibble)
        atomicAdd(&h[s >> 2], 16u << (8 * (s & 3)));   // out-count (high nibble)
    }
    __syncthreads();
    for (int i = tid; i < CWORDS; i += 1024)
        cntw[(size_t)team * CWORDS + i] = h[i];
    // fill colc (as uints) with 0xC350C350 = two ushort DUMMYs
    for (int i = blockIdx.x * 1024 + tid; i < N_NODES * 32; i += TEAMS * 1024)
        colc_fill[i] = 0xC350C350u;
}

// Pass 2: per-node exclusive prefix over the 256 team counts -> exact slot
// offsets. Hierarchical: 4 groups x 32 teams per phase, all 1024 threads
// active; group bases folded into the writeback as a packed-byte add.
__global__ __launch_bounds__(1024) void offsets_kernel(
    const unsigned* __restrict__ cntw, unsigned* __restrict__ offsw,
    unsigned* __restrict__ cnt_dense, float* __restrict__ c_src,
    float* __restrict__ c_dst)
{
    __shared__ unsigned ldsC[128 * 64];   // counts tile  (32 KB)
    __shared__ unsigned ldsO[128 * 64];   // local-prefix tile (32 KB)
    __shared__ unsigned totG[4 * 256];    // per-group (in | out<<16) totals
    __shared__ unsigned baseW[4 * 64];    // packed per-group base bytes
    int tid = threadIdx.x;
    int g = tid >> 8;            // group: 32 teams each within a phase
    int n = tid & 255;           // node-local index
    int n0 = blockIdx.x * 256;
    int w0 = n0 >> 2;
    unsigned carryIn = 0, carryOut = 0;
    for (int ph = 0; ph < 2; ++ph) {
        int t0 = ph * 128;
        for (int i = tid; i < 128 * 64; i += 1024) {
            int tl = i >> 6, wl = i & 63;
            int gw = w0 + wl;
            ldsC[i] = (gw < CWORDS) ? cntw[(size_t)(t0 + tl) * CWORDS + gw] : 0u;
        }
        __syncthreads();
        unsigned locIn = 0, locOut = 0;
        {
            unsigned char* ob = (unsigned char*)ldsO;
            for (int tl = g * 32; tl < g * 32 + 32; ++tl) {
                unsigned wvd = ldsC[tl * 64 + (n >> 2)];
                unsigned b = (wvd >> (8 * (n & 3))) & 255u;
                ob[tl * 256 + n] = (unsigned char)locIn;  // group-local prefix
                locIn  += (b & 15u);
                locOut += (b >> 4);
            }
        }
        totG[g * 256 + n] = locIn | (locOut << 16);
        __syncthreads();
        unsigned baseIn = 0, sumIn = 0, sumOut = 0;
#pragma unroll
        for (int gg = 0; gg < 4; ++gg) {
            unsigned t = totG[gg * 256 + n];
            if (gg < g) baseIn += (t & 0xffffu);
            sumIn += (t & 0xffffu); sumOut += (t >> 16);
        }
        ((unsigned char*)baseW)[g * 256 + n] = (unsigned char)(carryIn + baseIn);
        carryIn += sumIn; carryOut += sumOut;
        __syncthreads();
        for (int i = tid; i < 128 * 64; i += 1024) {
            int tl = i >> 6, wl = i & 63;
            int gw = w0 + wl;
            if (gw < CWORDS)
                offsw[(size_t)(t0 + tl) * CWORDS + gw] =
                    ldsO[i] + baseW[(tl >> 5) * 64 + wl];   // packed byte add
        }
        __syncthreads();
    }
    if (tid < 256) {
        int nn = n0 + tid;
        if (nn < N_NODES) {
            unsigned id_ = carryIn, od = carryOut;
            cnt_dense[nn] = id_ > 64u ? 64u : id_;
            if (id_ < 1u) id_ = 1u;
            if (od < 1u) od = 1u;
            c_dst[nn] = 1.0f / sqrtf((float)id_);
            c_src[nn] = 1.0f / sqrtf((float)od);
        }
    }
}

// Fused pass 3: scatter (blocks 0..255) + prescale (hsA = x*c_src, DUMMY row
// zeroed in both hs buffers) + wprep (W -> MFMA B-fragments).
__global__ __launch_bounds__(1024) void sp_kernel(
    const int* __restrict__ ei, const unsigned* __restrict__ offsw,
    unsigned short* __restrict__ colc,
    const float2* __restrict__ x, const float* __restrict__ c_src,
    unsigned* __restrict__ hsA, unsigned* __restrict__ hsB,
    const float* __restrict__ W0, const float* __restrict__ Ws,
    uint4* __restrict__ Wf)
{
    __shared__ unsigned h[CWORDS];      // 50 KB (scatter blocks only)
    int bid = blockIdx.x, tid = threadIdx.x;
    if (bid < SCAT_B) {
        int team = bid;
        for (int i = tid; i < CWORDS; i += 1024) h[i] = 0;
        __syncthreads();
        const unsigned char* __restrict__ ob =
            (const unsigned char*)offsw + (size_t)team * 50000;
        const int e0 = team * ESLICE;
        const int* __restrict__ srcp = ei;
        const int* __restrict__ dstp = ei + N_EDGES;
        for (int e = e0 + tid; e < e0 + ESLICE; e += 1024) {
            int s = srcp[e], d = dstp[e];
            unsigned old = atomicAdd(&h[d >> 2], 1u << (8 * (d & 3)));
            unsigned pos = (old >> (8 * (d & 3))) & 15u;
            unsigned slot = (unsigned)ob[d] + pos;
            if (slot < 64u) colc[(size_t)d * 64 + slot] = (unsigned short)s;
        }
        return;
    }
    if (bid < SCAT_B + PRE_B) {
        int i = (bid - SCAT_B) * 1024 + tid;     // over (N+1)*64 uints
        if (i >= (N_NODES + 1) * 64) return;
        int row = i >> 6;
        if (row < N_NODES) {
            float c = c_src[row];
            float2 v = x[i];
            hsA[i] = f2bf(v.x * c) | (f2bf(v.y * c) << 16);
        } else {
            hsA[i] = 0u;    // dummy row stays zero through all layers:
            hsB[i] = 0u;    // layer epilogues only write rows < N_NODES
        }
        return;
    }
    int t = (bid - SCAT_B - PRE_B) * 1024 + tid;
    if (t >= NLAYER * 2048) return;
    int layer = t >> 11;
    int rem = t & 2047;
    int lane = rem & 63;
    int s = (rem >> 6) & 3;
    int c = rem >> 8;
    int quad = lane >> 4, colw = c * 16 + (lane & 15);
    int k0 = s * 32 + quad * 8;
    const float* W = (layer == 0) ? W0 : Ws + (size_t)(layer - 1) * DIM * DIM;
    uint4 p;
    unsigned* pp = (unsigned*)&p;
#pragma unroll
    for (int j = 0; j < 4; ++j) {
        unsigned lo = f2bf(W[(size_t)(k0 + 2 * j) * DIM + colw]);
        unsigned hi = f2bf(W[(size_t)(k0 + 2 * j + 1) * DIM + colw]);
        pp[j] = lo | (hi << 16);
    }
    Wf[t] = p;
}

// Fused conv layer: block = 256 threads = 4 waves owns 16 rows.
// Phase A (4-node interleaved scalar-broadcast gather): the wave's 4 nodes
//   gather in ONE max(deg) loop -> 32 loads in flight; readlane broadcasts
//   keep the edge id on the scalar path (no LDS-pipe cross-lane ops).
//   Short nodes' tail slots read the DUMMY row (L1-hot zeros) -
//   masking-free. bf16 pack -> XOR-swizzled LDS A-tile.
//   (R17 A/B: per-node uniform-branch guards ambiguous under container
//   noise; flat interleave kept as the champion form.)
// Phase B: each wave MFMAs the 16-row tile over 2 of 8 column blocks.
// hs double-buffered across layers (in != out) to avoid cross-block races.
__global__ __launch_bounds__(256) void layer_kernel(
    const unsigned* __restrict__ hs, const unsigned short* __restrict__ colc,
    const unsigned* __restrict__ cnt_dense, const uint4* __restrict__ Wf,
    const float* __restrict__ bias, const float* __restrict__ c_dst,
    const float* __restrict__ c_src, unsigned short* __restrict__ out_bf,
    float* __restrict__ out_f32, int last)
{
    __shared__ unsigned Ash[16 * 64];    // 4 KB A-tile (16 rows x 256 B)
    char* Ab = (char*)Ash;
    int tid = threadIdx.x;
    int lane = tid & 63;
    int wv = __builtin_amdgcn_readfirstlane(tid >> 6);   // uniform wave id
    int r0 = blockIdx.x * 16;            // 3125 * 16 = 50000 exactly
    int nb = r0 + wv * 4;
    const unsigned* __restrict__ cw = (const unsigned*)colc;
    const char* __restrict__ hb = (const char*)hs;
    unsigned loff = (unsigned)(lane << 2);   // byte offset: feats 2*lane..+1

    unsigned dg0 = cnt_dense[nb + 0], dg1 = cnt_dense[nb + 1];
    unsigned dg2 = cnt_dense[nb + 2], dg3 = cnt_dense[nb + 3];
    unsigned m01 = dg0 > dg1 ? dg0 : dg1, m23 = dg2 > dg3 ? dg2 : dg3;
    unsigned mx = m01 > m23 ? m01 : m23;
    unsigned row0 = cw[(unsigned)(nb + 0) * 32u + (unsigned)(lane & 31)];
    unsigned row1 = cw[(unsigned)(nb + 1) * 32u + (unsigned)(lane & 31)];
    unsigned row2 = cw[(unsigned)(nb + 2) * 32u + (unsigned)(lane & 31)];
    unsigned row3 = cw[(unsigned)(nb + 3) * 32u + (unsigned)(lane & 31)];

    float f00 = 0.f, f01 = 0.f, f10 = 0.f, f11 = 0.f;
    float f20 = 0.f, f21 = 0.f, f30 = 0.f, f31 = 0.f;
    for (unsigned j = 0; j < mx; j += 8) {
#pragma unroll
        for (int k = 0; k < 4; ++k) {     // per k: 1 word per node = 8 edges
            int sl = (int)(j >> 1) + k;
            unsigned w0 = (unsigned)__builtin_amdgcn_readlane((int)row0, sl);
            unsigned w1 = (unsigned)__builtin_amdgcn_readlane((int)row1, sl);
            unsigned w2 = (unsigned)__builtin_amdgcn_readlane((int)row2, sl);
            unsigned w3 = (unsigned)__builtin_amdgcn_readlane((int)row3, sl);
            unsigned u00 = *(const unsigned*)(hb + ((w0 & 0xffffu) << 8) + loff);
            unsigned u01 = *(const unsigned*)(hb + ((w0 >> 16) << 8) + loff);
            unsigned u10 = *(const unsigned*)(hb + ((w1 & 0xffffu) << 8) + loff);
            unsigned u11 = *(const unsigned*)(hb + ((w1 >> 16) << 8) + loff);
            unsigned u20 = *(const unsigned*)(hb + ((w2 & 0xffffu) << 8) + loff);
            unsigned u21 = *(const unsigned*)(hb + ((w2 >> 16) << 8) + loff);
            unsigned u30 = *(const unsigned*)(hb + ((w3 & 0xffffu) << 8) + loff);
            unsigned u31 = *(const unsigned*)(hb + ((w3 >> 16) << 8) + loff);
            f00 += bf_lo(u00); f01 += bf_hi(u00);
            f00 += bf_lo(u01); f01 += bf_hi(u01);
            f10 += bf_lo(u10); f11 += bf_hi(u10);
            f10 += bf_lo(u11); f11 += bf_hi(u11);
            f20 += bf_lo(u20); f21 += bf_hi(u20);
            f20 += bf_lo(u21); f21 += bf_hi(u21);
            f30 += bf_lo(u30); f31 += bf_hi(u30);
            f30 += bf_lo(u31); f31 += bf_hi(u31);
        }
    }
    {
        int il = wv * 4;
        *(unsigned*)(Ab + il * 256 + ((lane << 2) ^ ((il & 7) << 4))) =
            f2bf(f00) | (f2bf(f01) << 16);
        il++;
        *(unsigned*)(Ab + il * 256 + ((lane << 2) ^ ((il & 7) << 4))) =
            f2bf(f10) | (f2bf(f11) << 16);
        il++;
        *(unsigned*)(Ab + il * 256 + ((lane << 2) ^ ((il & 7) << 4))) =
            f2bf(f20) | (f2bf(f21) << 16);
        il++;
        *(unsigned*)(Ab + il * 256 + ((lane << 2) ^ ((il & 7) << 4))) =
            f2bf(f30) | (f2bf(f31) << 16);
    }
    __syncthreads();

    int quad = lane >> 4, m16 = lane & 15;
    union U { uint4 u; short8 s; };
    U a[4];
#pragma unroll
    for (int s = 0; s < 4; ++s)
        a[s].u = *(const uint4*)(
            Ab + m16 * 256 + ((s * 64 + quad * 16) ^ ((m16 & 7) << 4)));

    floatx4 acc[2];
#pragma unroll
    for (int cc = 0; cc < 2; ++cc) {
        int c = wv * 2 + cc;
        floatx4 ac = {0.f, 0.f, 0.f, 0.f};
#pragma unroll
        for (int s = 0; s < 4; ++s) {
            U b; b.u = Wf[(c * 4 + s) * 64 + lane];
            ac = __builtin_amdgcn_mfma_f32_16x16x32_bf16(a[s].s, b.s, ac, 0, 0, 0);
        }
        acc[cc] = ac;
    }

    float cd[4], cs[4];
#pragma unroll
    for (int r = 0; r < 4; ++r) {
        int row = r0 + quad * 4 + r;
        cd[r] = c_dst[row];
        cs[r] = last ? 1.f : c_src[row];
    }
#pragma unroll
    for (int cc = 0; cc < 2; ++cc) {
        int colg = (wv * 2 + cc) * 16 + m16;
        float b = bias[colg];
#pragma unroll
        for (int r = 0; r < 4; ++r) {
            int row = r0 + quad * 4 + r;
            float v = acc[cc][r] * cd[r] + b;
            v = v > 0.f ? v : 0.f;
            if (last) out_f32[(size_t)row * DIM + colg] = v;
            else      out_bf[(size_t)row * DIM + colg] = (unsigned short)f2bf(v * cs[r]);
        }
    }
}

// Fused readout+head, MLP-fixed: one block per graph, 512 threads = 4
// row-lanes x 128 cols. Each thread keeps EIGHT independent accumulators
// (rows n, n+4, ..., n+28 per 32-row window) -> 8 loads in flight per
// thread instead of a serial stride-4 chain (the R18 version's ~1-2).
// Zero atomics, no hg/cntg buffers, one launch.
__global__ __launch_bounds__(512) void graph_kernel(
    const float* __restrict__ h, const int* __restrict__ gid,
    const float* __restrict__ Wc, const float* __restrict__ bc,
    float* __restrict__ out)
{
    __shared__ float part[512];
    __shared__ float hgv[DIM];
    int g = blockIdx.x;               // 0..NGRAPH-1
    int tid = threadIdx.x;
    // lower_bound(g) and lower_bound(g+1) on sorted gid
    int lo = 0, hi = N_NODES;
    while (lo < hi) { int mid = (lo + hi) >> 1; if (gid[mid] < g) lo = mid + 1; else hi = mid; }
    int start = lo;
    hi = N_NODES;
    while (lo < hi) { int mid = (lo + hi) >> 1; if (gid[mid] < g + 1) lo = mid + 1; else hi = mid; }
    int end = lo;

    int j = tid & 127, q = tid >> 7;  // q in 0..3
    float a0 = 0.f, a1 = 0.f, a2 = 0.f, a3 = 0.f;
    float a4 = 0.f, a5 = 0.f, a6 = 0.f, a7 = 0.f;
    int n = start + q;
    for (; n + 28 < end; n += 32) {   // 8 independent loads in flight
        a0 += h[(size_t)(n     ) * DIM + j];
        a1 += h[(size_t)(n +  4) * DIM + j];
        a2 += h[(size_t)(n +  8) * DIM + j];
        a3 += h[(size_t)(n + 12) * DIM + j];
        a4 += h[(size_t)(n + 16) * DIM + j];
        a5 += h[(size_t)(n + 20) * DIM + j];
        a6 += h[(size_t)(n + 24) * DIM + j];
        a7 += h[(size_t)(n + 28) * DIM + j];
    }
    for (; n < end; n += 4)
        a0 += h[(size_t)n * DIM + j];
    part[tid] = ((a0 + a1) + (a2 + a3)) + ((a4 + a5) + (a6 + a7));
    __syncthreads();
    if (tid < DIM) {
        float s = part[tid] + part[tid + 128] + part[tid + 256] + part[tid + 384];
        hgv[tid] = s / fmaxf((float)(end - start), 1.0f);
    }
    __syncthreads();
    if (tid < NCLASS) {
        float s = 0.f;
#pragma unroll 8
        for (int jj = 0; jj < DIM; ++jj)
            s = fmaf(hgv[jj], Wc[jj * NCLASS + tid], s);
        out[g * NCLASS + tid] = s + bc[tid];
    }
}

// ---------------------------------------------------------------------------
extern "C" void kernel_launch(void* const* d_in, const int* in_sizes, int n_in,
                              void* d_out, int out_size, void* d_ws, size_t ws_size,
                              hipStream_t stream)
{
    const float* x   = (const float*)d_in[0];
    const float* W0  = (const float*)d_in[1];
    const float* b0  = (const float*)d_in[2];
    const float* Ws  = (const float*)d_in[3];
    const float* bs  = (const float*)d_in[4];
    const float* Wc  = (const float*)d_in[5];
    const float* bc  = (const float*)d_in[6];
    const int*   ei  = (const int*)d_in[7];
    const int*   gid = (const int*)d_in[8];
    float* out = (float*)d_out;

    char* ws = (char*)d_ws;
    size_t o = 0;
    auto alloc = [&](size_t bytes) {
        size_t r = o; o = (o + bytes + 255) & ~(size_t)255; return r;
    };
    unsigned* cntw      = (unsigned*)(ws + alloc((size_t)TEAMS * CWORDS * 4));
    unsigned* offsw     = (unsigned*)(ws + alloc((size_t)TEAMS * CWORDS * 4));
    unsigned* cnt_dense = (unsigned*)(ws + alloc((size_t)N_NODES * 4));
    float*    c_src     = (float*)(ws + alloc((size_t)N_NODES * 4));
    float*    c_dst     = (float*)(ws + alloc((size_t)N_NODES * 4));
    unsigned short* colc = (unsigned short*)(ws + alloc((size_t)N_NODES * 64 * 2));
    unsigned* hsA       = (unsigned*)(ws + alloc((size_t)(N_NODES + 1) * 64 * 4));
    unsigned* hsB       = (unsigned*)(ws + alloc((size_t)(N_NODES + 1) * 64 * 4));
    float*    hlast     = (float*)(ws + alloc((size_t)N_NODES * DIM * 4));
    uint4*    Wf        = (uint4*)(ws + alloc((size_t)NLAYER * 2048 * 16));

    count_kernel<<<TEAMS, 1024, 0, stream>>>(ei, cntw, (unsigned*)colc);
    offsets_kernel<<<(N_NODES + 255) / 256, 1024, 0, stream>>>(
        cntw, offsw, cnt_dense, c_src, c_dst);
    sp_kernel<<<SCAT_B + PRE_B + W_B, 1024, 0, stream>>>(
        ei, offsw, colc, (const float2*)x, c_src, hsA, hsB, W0, Ws, Wf);

    const int LAYER_BLOCKS = N_NODES / 16;   // 3125, exact

    for (int l = 0; l < NLAYER; ++l) {
        const float* b = (l == 0) ? b0 : (bs + (size_t)(l - 1) * DIM);
        int last = (l == NLAYER - 1) ? 1 : 0;
        const unsigned* hin = (l & 1) ? hsB : hsA;
        unsigned* hout      = (l & 1) ? hsA : hsB;
        layer_kernel<<<LAYER_BLOCKS, 256, 0, stream>>>(
            hin, colc, cnt_dense, Wf + (size_t)l * 2048, b, c_dst, c_src,
            (unsigned short*)hout, hlast, last);
    }

    graph_kernel<<<NGRAPH, 512, 0, stream>>>(hlast, gid, Wc, bc, out);
}